// Round 4
// baseline (1249.975 us; speedup 1.0000x reference)
//
#include <hip/hip_runtime.h>
#include <math.h>

typedef __attribute__((ext_vector_type(8))) short bf16x8;
typedef __attribute__((ext_vector_type(4))) float f32x4;
typedef __attribute__((ext_vector_type(2))) float f32x2;

static __device__ __forceinline__ unsigned short f2bf(float f) {
  unsigned u = __float_as_uint(f);
  unsigned r = (u + 0x7FFF + ((u >> 16) & 1)) >> 16; // RNE
  return (unsigned short)r;
}
static __device__ __forceinline__ float bf2f(unsigned short b) {
  return __uint_as_float(((unsigned)b) << 16);
}

// DPP add: x += lane-permuted x (ctrl must be an immediate)
#define DPP_ADD(x, ctrl) \
  ((x) + __int_as_float(__builtin_amdgcn_update_dpp(0, __float_as_int(x), (ctrl), 0xf, 0xf, false)))

// ---------------- CSR build ----------------

__global__ void k_degree(const int* __restrict__ dst, int* __restrict__ deg, int E) {
  int e = blockIdx.x * 256 + threadIdx.x;
  if (e < E) atomicAdd(&deg[dst[e]], 1);
}

__global__ void k_scan1(const int* __restrict__ deg, int* __restrict__ part,
                        int* __restrict__ bs, int N) {
  __shared__ int s[256];
  int gid = blockIdx.x * 256 + threadIdx.x;
  int v = (gid < N) ? deg[gid] : 0;
  s[threadIdx.x] = v;
  __syncthreads();
  for (int off = 1; off < 256; off <<= 1) {
    int t = (threadIdx.x >= off) ? s[threadIdx.x - off] : 0;
    __syncthreads();
    s[threadIdx.x] += t;
    __syncthreads();
  }
  if (gid < N) part[gid] = s[threadIdx.x] - v;
  if (threadIdx.x == 255) bs[blockIdx.x] = s[255];
}

__global__ void k_scan2(int* __restrict__ bs, int nb) {
  __shared__ int s[256];
  int v = (threadIdx.x < nb) ? bs[threadIdx.x] : 0;
  s[threadIdx.x] = v;
  __syncthreads();
  for (int off = 1; off < 256; off <<= 1) {
    int t = (threadIdx.x >= off) ? s[threadIdx.x - off] : 0;
    __syncthreads();
    s[threadIdx.x] += t;
    __syncthreads();
  }
  if (threadIdx.x < nb) bs[threadIdx.x] = s[threadIdx.x] - v;
}

__global__ void k_scan3(int* __restrict__ rowptr, const int* __restrict__ bs,
                        int* __restrict__ cursor, int N, int E) {
  int gid = blockIdx.x * 256 + threadIdx.x;
  if (gid < N) {
    int v = rowptr[gid] + bs[blockIdx.x];
    rowptr[gid] = v;
    cursor[gid] = v;
  }
  if (gid == 0) rowptr[N] = E;
}

__global__ void k_fill(const int* __restrict__ src, const int* __restrict__ dst,
                       int* __restrict__ cursor, int* __restrict__ colb, int E) {
  int e = blockIdx.x * 256 + threadIdx.x;
  if (e < E) {
    int p = atomicAdd(&cursor[dst[e]], 1);
    colb[p] = src[e] << 9; // byte offset into bf16 rows (256 bf16 = 512 B)
  }
}

// ---------------- W prep: fp32 [64][256] -> bf16 transposed [256][64] ----------------
// wt layout: mat m (0..5 = Wl1,Wr1,Wl2,Wr2,Wl3,Wr3) at wt + m*16384

__global__ __launch_bounds__(256) void k_wprep(const float* __restrict__ W0, const float* __restrict__ W1,
                                               const float* __restrict__ W2, const float* __restrict__ W3,
                                               const float* __restrict__ W4, const float* __restrict__ W5,
                                               unsigned short* __restrict__ wt) {
  int gid = blockIdx.x * 256 + threadIdx.x; // 6 * 16384
  int m = gid >> 14;
  int r = gid & 16383;
  int k = r >> 8;    // 0..63
  int n = r & 255;   // 0..255
  const float* W = (m == 0) ? W0 : (m == 1) ? W1 : (m == 2) ? W2
                 : (m == 3) ? W3 : (m == 4) ? W4 : W5;
  wt[(size_t)m * 16384 + n * 64 + k] = f2bf(W[k * 256 + n]);
}

// ---------------- MFMA dual GEMM, persistent B: out = h @ W ----------------
// grid (GX, 4): y 0,1 -> Wl cols 0-127/128-255 -> xlb; y 2,3 -> Wr -> xrb.
// B (bf16 W slice) staged once per block; grid-stride over 32-row tiles.
// Compensation: acc = Ah*Bh + Al*Bh (A split hi/lo; B single bf16).

__global__ __launch_bounds__(256) void k_mm(const float* __restrict__ h,
                                            const unsigned short* __restrict__ wt,
                                            unsigned short* __restrict__ xlb,
                                            unsigned short* __restrict__ xrb,
                                            int N, int ntiles) {
  __shared__ unsigned short Ah[32][72], Al[32][72];
  __shared__ unsigned short Bh[128][72];
  const int t = threadIdx.x;
  const bool isL = (blockIdx.y < 2);
  const int coff = (blockIdx.y & 1) * 128;
  const unsigned short* wb = wt + (isL ? 0 : 16384);
  unsigned short* dst = isL ? xlb : xrb;

  // stage B once (128 cols x 64 k)
#pragma unroll
  for (int j = 0; j < 4; ++j) {
    int cidx = t + 256 * j; // 0..1023 chunks of 8 shorts
    int n = cidx >> 3, k0 = (cidx & 7) * 8;
    *(bf16x8*)&Bh[n][k0] = *(const bf16x8*)(wb + (size_t)(coff + n) * 64 + k0);
  }

  const int wave = t >> 6, lane = t & 63;
  const int rw = (wave & 1) * 16, cw = (wave >> 1) * 64;
  const int m15 = lane & 15, quad = lane >> 4;
  const int arow = t >> 3, ac0 = (t & 7) * 8;

  for (int tile = blockIdx.x; tile < ntiles; tile += gridDim.x) {
    int r0 = tile * 32;
    // stage A (fp32 -> bf16 hi/lo)
    {
      int gr = r0 + arow;
      float4 v0 = {0, 0, 0, 0}, v1 = {0, 0, 0, 0};
      if (gr < N) {
        v0 = *(const float4*)(h + (size_t)gr * 64 + ac0);
        v1 = *(const float4*)(h + (size_t)gr * 64 + ac0 + 4);
      }
      float vs[8] = {v0.x, v0.y, v0.z, v0.w, v1.x, v1.y, v1.z, v1.w};
      bf16x8 hi8, lo8;
#pragma unroll
      for (int i = 0; i < 8; ++i) {
        unsigned short hh = f2bf(vs[i]);
        hi8[i] = (short)hh;
        lo8[i] = (short)f2bf(vs[i] - bf2f(hh));
      }
      *(bf16x8*)&Ah[arow][ac0] = hi8;
      *(bf16x8*)&Al[arow][ac0] = lo8;
    }
    __syncthreads();

    f32x4 acc[4] = {{0, 0, 0, 0}, {0, 0, 0, 0}, {0, 0, 0, 0}, {0, 0, 0, 0}};
#pragma unroll
    for (int kk = 0; kk < 64; kk += 32) {
      bf16x8 ah = *(const bf16x8*)&Ah[rw + m15][kk + quad * 8];
      bf16x8 al = *(const bf16x8*)&Al[rw + m15][kk + quad * 8];
#pragma unroll
      for (int s = 0; s < 4; ++s) {
        bf16x8 bh = *(const bf16x8*)&Bh[cw + s * 16 + m15][kk + quad * 8];
        acc[s] = __builtin_amdgcn_mfma_f32_16x16x32_bf16(ah, bh, acc[s], 0, 0, 0);
        acc[s] = __builtin_amdgcn_mfma_f32_16x16x32_bf16(al, bh, acc[s], 0, 0, 0);
      }
    }
    // C/D: col = lane&15, row = quad*4 + reg
#pragma unroll
    for (int s = 0; s < 4; ++s) {
#pragma unroll
      for (int r = 0; r < 4; ++r) {
        int row_g = r0 + rw + quad * 4 + r;
        if (row_g < N)
          dst[(size_t)row_g * 256 + coff + cw + s * 16 + m15] = f2bf(acc[s][r]);
      }
    }
    __syncthreads();
  }
}

// ---------------- GATv2: wave per node, head-major lanes, packed f32, fused BN stats ----------

__global__ __launch_bounds__(256) void k_gat(const unsigned short* __restrict__ xlb,
                                             const unsigned short* __restrict__ xrb,
                                             const float* __restrict__ att,
                                             const float* __restrict__ bias,
                                             const int* __restrict__ rowptr,
                                             const int* __restrict__ colb,
                                             float* __restrict__ out,
                                             float* __restrict__ bnsum, int N) {
  __shared__ float sres[4][64];
  const int wv = threadIdx.x >> 6;
  const int node = blockIdx.x * 4 + wv;
  const int lane = threadIdx.x & 63;
  const bool valid = node < N;
  const int nsafe = valid ? node : 0;
  float4 a4 = *(const float4*)(att + lane * 4);
  const float LOG2E = 1.4426950408889634f;
  const f32x2 a01 = {a4.x * LOG2E, a4.y * LOG2E};
  const f32x2 a23 = {a4.z * LOG2E, a4.w * LOG2E};
  const f32x2 c02 = {0.2f, 0.2f};
  const char* base = (const char*)xlb + (size_t)lane * 8;
  uint2 xru = *(const uint2*)((const char*)xrb + (size_t)nsafe * 512 + lane * 8);
  const f32x2 xr01 = {__uint_as_float(xru.x << 16), __uint_as_float(xru.x & 0xFFFF0000u)};
  const f32x2 xr23 = {__uint_as_float(xru.y << 16), __uint_as_float(xru.y & 0xFFFF0000u)};
  int beg = rowptr[nsafe];
  int end = valid ? rowptr[nsafe + 1] : beg - 1;
  float m = -INFINITY, lsum = 0.f;
  f32x2 o01 = {0.f, 0.f}, o23 = {0.f, 0.f};
  uint2 vb_next = *(const uint2*)(base + (size_t)(unsigned)nsafe * 512);
  int off_n = (beg < end) ? colb[beg] : 0;
  for (int e = beg; e <= end; ++e) {
    uint2 vb = vb_next;
    int off = off_n;
    if (e + 1 < end) off_n = colb[e + 1];
    if (e < end) vb_next = *(const uint2*)(base + (size_t)(unsigned)off);
    f32x2 v01 = {__uint_as_float(vb.x << 16), __uint_as_float(vb.x & 0xFFFF0000u)};
    f32x2 v23 = {__uint_as_float(vb.y << 16), __uint_as_float(vb.y & 0xFFFF0000u)};
    f32x2 s01 = v01 + xr01;
    f32x2 s23 = v23 + xr23;
    s01 = __builtin_elementwise_max(s01, s01 * c02);
    s23 = __builtin_elementwise_max(s23, s23 * c02);
    f32x2 q = __builtin_elementwise_fma(s23, a23, s01 * a01);
    float p = q.x + q.y;
    // sum over the 16-lane head group, pure VALU (quad_perm xor1, xor2; row_ror 4, 8)
    p = DPP_ADD(p, 0xB1);
    p = DPP_ADD(p, 0x4E);
    p = DPP_ADD(p, 0x124);
    p = DPP_ADD(p, 0x128);
    float nm = fmaxf(m, p);
    float sc = __builtin_amdgcn_exp2f(m - nm);
    float w = __builtin_amdgcn_exp2f(p - nm);
    lsum = fmaf(lsum, sc, w);
    f32x2 sc2 = {sc, sc}, w2 = {w, w};
    o01 = __builtin_elementwise_fma(o01, sc2, w2 * v01);
    o23 = __builtin_elementwise_fma(o23, sc2, w2 * v23);
    m = nm;
  }
  float inv = __builtin_amdgcn_rcpf(lsum);
  float rx = o01.x * inv, ry = o01.y * inv, rz = o23.x * inv, rw2 = o23.y * inv;
  rx += __shfl_xor(rx, 16, 64); rx += __shfl_xor(rx, 32, 64);
  ry += __shfl_xor(ry, 16, 64); ry += __shfl_xor(ry, 32, 64);
  rz += __shfl_xor(rz, 16, 64); rz += __shfl_xor(rz, 32, 64);
  rw2 += __shfl_xor(rw2, 16, 64); rw2 += __shfl_xor(rw2, 32, 64);
  if (lane < 16) {
    float4 res = {0.f, 0.f, 0.f, 0.f};
    if (valid) {
      float4 b4 = *(const float4*)(bias + lane * 4);
      res.x = 0.25f * rx + b4.x;
      res.y = 0.25f * ry + b4.y;
      res.z = 0.25f * rz + b4.z;
      res.w = 0.25f * rw2 + b4.w;
      *(float4*)(out + (size_t)node * 64 + lane * 4) = res;
    }
    *(float4*)&sres[wv][lane * 4] = res; // zeros for invalid -> stats unaffected
  }
  __syncthreads();
  if (threadIdx.x < 64) {
    int c = threadIdx.x;
    float s0 = sres[0][c], s1 = sres[1][c], s2 = sres[2][c], s3 = sres[3][c];
    atomicAdd(&bnsum[c], s0 + s1 + s2 + s3);
    atomicAdd(&bnsum[64 + c], s0 * s0 + s1 * s1 + s2 * s2 + s3 * s3);
  }
}

// ---------------- BN apply (+GELU +residual +optional pool) ----------------

__global__ __launch_bounds__(256) void k_bn_apply(const float* __restrict__ gat,
                                                  const float* __restrict__ sums,
                                                  const float* __restrict__ g,
                                                  const float* __restrict__ be,
                                                  const float* __restrict__ resid,
                                                  float* __restrict__ out,
                                                  const int* __restrict__ batch,
                                                  float* __restrict__ pool,
                                                  int total, float inv_n) {
  int idx = blockIdx.x * 256 + threadIdx.x;
  if (idx >= total) return;
  int c = idx & 63;
  float mu = sums[c] * inv_n;
  float var = sums[64 + c] * inv_n - mu * mu;
  float inv = rsqrtf(var + 1e-5f);
  float v = g[c] * (gat[idx] - mu) * inv + be[c];
  float ge = 0.5f * v * (1.f + erff(v * 0.70710678118654752f));
  float val = ge + (resid ? resid[idx] : 0.f);
  out[idx] = val;
  if (pool) atomicAdd(&pool[(size_t)batch[idx >> 6] * 64 + c], val);
}

// ---------------- heads ----------------

__global__ void k_head(const float* __restrict__ pool, const float* __restrict__ Wmu,
                       const float* __restrict__ bmu, const float* __restrict__ Wlv,
                       const float* __restrict__ blv, float* __restrict__ out, int G) {
  int g = blockIdx.x;
  int c = threadIdx.x; // 64 threads
  __shared__ float row[64];
  row[c] = pool[(size_t)g * 64 + c];
  __syncthreads();
  float am = 0.f, al = 0.f;
  for (int k = 0; k < 64; ++k) {
    float r = row[k];
    am = fmaf(r, Wmu[k * 64 + c], am);
    al = fmaf(r, Wlv[k * 64 + c], al);
  }
  out[(size_t)g * 64 + c] = am + bmu[c];
  out[(size_t)G * 64 + (size_t)g * 64 + c] = al + blv[c];
}

// ---------------- launch ----------------

extern "C" void kernel_launch(void* const* d_in, const int* in_sizes, int n_in,
                              void* d_out, int out_size, void* d_ws, size_t ws_size,
                              hipStream_t stream) {
  const float* x    = (const float*)d_in[0];
  const int* esrc   = (const int*)d_in[1];
  const int* edst   = (const int*)d_in[2];
  const int* batch  = (const int*)d_in[3];
  const float* Wl[3]  = {(const float*)d_in[5],  (const float*)d_in[11], (const float*)d_in[17]};
  const float* Wr[3]  = {(const float*)d_in[6],  (const float*)d_in[12], (const float*)d_in[18]};
  const float* att[3] = {(const float*)d_in[7],  (const float*)d_in[13], (const float*)d_in[19]};
  const float* bia[3] = {(const float*)d_in[8],  (const float*)d_in[14], (const float*)d_in[20]};
  const float* gam[3] = {(const float*)d_in[9],  (const float*)d_in[15], (const float*)d_in[21]};
  const float* bet[3] = {(const float*)d_in[10], (const float*)d_in[16], (const float*)d_in[22]};
  const float* Wmu = (const float*)d_in[23];
  const float* bmu = (const float*)d_in[24];
  const float* Wlv = (const float*)d_in[25];
  const float* blv = (const float*)d_in[26];
  float* out = (float*)d_out;

  const int N = in_sizes[0] / 64;
  const int E = in_sizes[1];
  const int G = out_size / 128;

  char* p = (char*)d_ws;
  auto alloc = [&](size_t bytes) -> void* {
    void* r = (void*)p;
    p += (bytes + 255) & ~(size_t)255;
    return r;
  };
  // zero-init region first (one memset covers deg + bnsum + pool)
  int*   deg    = (int*)alloc((size_t)N * 4);
  float* bnsum  = (float*)alloc(3 * 128 * 4);
  float* pool   = (float*)alloc((size_t)G * 64 * 4);
  char*  zend   = p;
  unsigned short* xlb = (unsigned short*)alloc((size_t)N * 256 * 2);
  unsigned short* xrb = (unsigned short*)alloc((size_t)N * 256 * 2);
  float* hA     = (float*)alloc((size_t)N * 64 * 4);
  float* hB     = (float*)alloc((size_t)N * 64 * 4);
  float* gat    = (float*)alloc((size_t)N * 64 * 4);
  int*   rowptr = (int*)alloc((size_t)(N + 1) * 4);
  int*   cursor = (int*)alloc((size_t)N * 4);
  int*   bs     = (int*)alloc(256 * 4);
  int*   colb   = (int*)alloc((size_t)E * 4);
  unsigned short* wt = (unsigned short*)alloc(6 * 16384 * 2);

  const int nbN   = (N + 255) / 256;
  const int nbE   = (E + 255) / 256;
  const int nbGat = (N + 3) / 4;
  const int nbEl  = (N * 64 + 255) / 256;
  const int ntiles = (N + 31) / 32;
  const float inv_n = 1.f / (float)N;

  hipMemsetAsync(deg, 0, (size_t)(zend - (char*)deg), stream);

  // ---- W prep + CSR build ----
  k_wprep<<<6 * 64, 256, 0, stream>>>(Wl[0], Wr[0], Wl[1], Wr[1], Wl[2], Wr[2], wt);
  k_degree<<<nbE, 256, 0, stream>>>(edst, deg, E);
  k_scan1<<<nbN, 256, 0, stream>>>(deg, rowptr, bs, N);
  k_scan2<<<1, 256, 0, stream>>>(bs, nbN);
  k_scan3<<<nbN, 256, 0, stream>>>(rowptr, bs, cursor, N, E);
  k_fill<<<nbE, 256, 0, stream>>>(esrc, edst, cursor, colb, E);

  // ---- 3 GATv2 + BN + GELU (+res) layers ----
  const float* hin = x;
  float* houts[3] = {hA, hB, hA};
  for (int L = 0; L < 3; ++L) {
    float* hout = houts[L];
    const float* resid = (L == 0) ? nullptr : hin;
    float* poolArg = (L == 2) ? pool : nullptr;
    dim3 gmm(256, 4);
    k_mm<<<gmm, 256, 0, stream>>>(hin, wt + (size_t)L * 32768, xlb, xrb, N, ntiles);
    k_gat<<<nbGat, 256, 0, stream>>>(xlb, xrb, att[L], bia[L], rowptr, colb, gat,
                                     bnsum + 128 * L, N);
    k_bn_apply<<<nbEl, 256, 0, stream>>>(gat, bnsum + 128 * L, gam[L], bet[L], resid, hout,
                                         batch, poolArg, N * 64, inv_n);
    hin = hout;
  }

  k_head<<<G, 64, 0, stream>>>(pool, Wmu, bmu, Wlv, blv, out, G);
}

// Round 5
// 575.654 us; speedup vs baseline: 2.1714x; 2.1714x over previous
//
#include <hip/hip_runtime.h>
#include <math.h>

typedef __attribute__((ext_vector_type(8))) short bf16x8;
typedef __attribute__((ext_vector_type(4))) float f32x4;
typedef __attribute__((ext_vector_type(2))) float f32x2;

static __device__ __forceinline__ unsigned short f2bf(float f) {
  unsigned u = __float_as_uint(f);
  unsigned r = (u + 0x7FFF + ((u >> 16) & 1)) >> 16; // RNE
  return (unsigned short)r;
}
static __device__ __forceinline__ float bf2f(unsigned short b) {
  return __uint_as_float(((unsigned)b) << 16);
}

// DPP add: x += lane-permuted x (ctrl must be an immediate)
#define DPP_ADD(x, ctrl) \
  ((x) + __int_as_float(__builtin_amdgcn_update_dpp(0, __float_as_int(x), (ctrl), 0xf, 0xf, false)))

// ---------------- CSR build ----------------

__global__ void k_degree(const int* __restrict__ dst, int* __restrict__ deg, int E) {
  int e = blockIdx.x * 256 + threadIdx.x;
  if (e < E) atomicAdd(&deg[dst[e]], 1);
}

__global__ void k_scan1(const int* __restrict__ deg, int* __restrict__ part,
                        int* __restrict__ bs, int N) {
  __shared__ int s[256];
  int gid = blockIdx.x * 256 + threadIdx.x;
  int v = (gid < N) ? deg[gid] : 0;
  s[threadIdx.x] = v;
  __syncthreads();
  for (int off = 1; off < 256; off <<= 1) {
    int t = (threadIdx.x >= off) ? s[threadIdx.x - off] : 0;
    __syncthreads();
    s[threadIdx.x] += t;
    __syncthreads();
  }
  if (gid < N) part[gid] = s[threadIdx.x] - v;
  if (threadIdx.x == 255) bs[blockIdx.x] = s[255];
}

__global__ void k_scan2(int* __restrict__ bs, int nb) {
  __shared__ int s[256];
  int v = (threadIdx.x < nb) ? bs[threadIdx.x] : 0;
  s[threadIdx.x] = v;
  __syncthreads();
  for (int off = 1; off < 256; off <<= 1) {
    int t = (threadIdx.x >= off) ? s[threadIdx.x - off] : 0;
    __syncthreads();
    s[threadIdx.x] += t;
    __syncthreads();
  }
  if (threadIdx.x < nb) bs[threadIdx.x] = s[threadIdx.x] - v;
}

__global__ void k_scan3(int* __restrict__ rowptr, const int* __restrict__ bs,
                        int* __restrict__ cursor, int N, int E) {
  int gid = blockIdx.x * 256 + threadIdx.x;
  if (gid < N) {
    int v = rowptr[gid] + bs[blockIdx.x];
    rowptr[gid] = v;
    cursor[gid] = v;
  }
  if (gid == 0) rowptr[N] = E;
}

__global__ void k_fill(const int* __restrict__ src, const int* __restrict__ dst,
                       int* __restrict__ cursor, int* __restrict__ colb, int E) {
  int e = blockIdx.x * 256 + threadIdx.x;
  if (e < E) {
    int p = atomicAdd(&cursor[dst[e]], 1);
    colb[p] = src[e] << 9; // byte offset into bf16 rows (256 bf16 = 512 B)
  }
}

// ---------------- W prep: fp32 [64][256] -> bf16 transposed [256][64] ----------------
// wt layout: mat m (0..5 = Wl1,Wr1,Wl2,Wr2,Wl3,Wr3) at wt + m*16384

__global__ __launch_bounds__(256) void k_wprep(const float* __restrict__ W0, const float* __restrict__ W1,
                                               const float* __restrict__ W2, const float* __restrict__ W3,
                                               const float* __restrict__ W4, const float* __restrict__ W5,
                                               unsigned short* __restrict__ wt) {
  int gid = blockIdx.x * 256 + threadIdx.x; // 6 * 16384
  int m = gid >> 14;
  int r = gid & 16383;
  int k = r >> 8;    // 0..63
  int n = r & 255;   // 0..255
  const float* W = (m == 0) ? W0 : (m == 1) ? W1 : (m == 2) ? W2
                 : (m == 3) ? W3 : (m == 4) ? W4 : W5;
  wt[(size_t)m * 16384 + n * 64 + k] = f2bf(W[k * 256 + n]);
}

// ---------------- MFMA dual GEMM, persistent B: out = h @ W ----------------
// grid (GX, 4): y 0,1 -> Wl cols 0-127/128-255 -> xlb; y 2,3 -> Wr -> xrb.
// B (bf16 W slice) staged once per block; grid-stride over 32-row tiles.
// Compensation: acc = Ah*Bh + Al*Bh (A split hi/lo; B single bf16).

__global__ __launch_bounds__(256) void k_mm(const float* __restrict__ h,
                                            const unsigned short* __restrict__ wt,
                                            unsigned short* __restrict__ xlb,
                                            unsigned short* __restrict__ xrb,
                                            int N, int ntiles) {
  __shared__ unsigned short Ah[32][72], Al[32][72];
  __shared__ unsigned short Bh[128][72];
  const int t = threadIdx.x;
  const bool isL = (blockIdx.y < 2);
  const int coff = (blockIdx.y & 1) * 128;
  const unsigned short* wb = wt + (isL ? 0 : 16384);
  unsigned short* dst = isL ? xlb : xrb;

  // stage B once (128 cols x 64 k)
#pragma unroll
  for (int j = 0; j < 4; ++j) {
    int cidx = t + 256 * j; // 0..1023 chunks of 8 shorts
    int n = cidx >> 3, k0 = (cidx & 7) * 8;
    *(bf16x8*)&Bh[n][k0] = *(const bf16x8*)(wb + (size_t)(coff + n) * 64 + k0);
  }

  const int wave = t >> 6, lane = t & 63;
  const int rw = (wave & 1) * 16, cw = (wave >> 1) * 64;
  const int m15 = lane & 15, quad = lane >> 4;
  const int arow = t >> 3, ac0 = (t & 7) * 8;

  for (int tile = blockIdx.x; tile < ntiles; tile += gridDim.x) {
    int r0 = tile * 32;
    // stage A (fp32 -> bf16 hi/lo)
    {
      int gr = r0 + arow;
      float4 v0 = {0, 0, 0, 0}, v1 = {0, 0, 0, 0};
      if (gr < N) {
        v0 = *(const float4*)(h + (size_t)gr * 64 + ac0);
        v1 = *(const float4*)(h + (size_t)gr * 64 + ac0 + 4);
      }
      float vs[8] = {v0.x, v0.y, v0.z, v0.w, v1.x, v1.y, v1.z, v1.w};
      bf16x8 hi8, lo8;
#pragma unroll
      for (int i = 0; i < 8; ++i) {
        unsigned short hh = f2bf(vs[i]);
        hi8[i] = (short)hh;
        lo8[i] = (short)f2bf(vs[i] - bf2f(hh));
      }
      *(bf16x8*)&Ah[arow][ac0] = hi8;
      *(bf16x8*)&Al[arow][ac0] = lo8;
    }
    __syncthreads();

    f32x4 acc[4] = {{0, 0, 0, 0}, {0, 0, 0, 0}, {0, 0, 0, 0}, {0, 0, 0, 0}};
#pragma unroll
    for (int kk = 0; kk < 64; kk += 32) {
      bf16x8 ah = *(const bf16x8*)&Ah[rw + m15][kk + quad * 8];
      bf16x8 al = *(const bf16x8*)&Al[rw + m15][kk + quad * 8];
#pragma unroll
      for (int s = 0; s < 4; ++s) {
        bf16x8 bh = *(const bf16x8*)&Bh[cw + s * 16 + m15][kk + quad * 8];
        acc[s] = __builtin_amdgcn_mfma_f32_16x16x32_bf16(ah, bh, acc[s], 0, 0, 0);
        acc[s] = __builtin_amdgcn_mfma_f32_16x16x32_bf16(al, bh, acc[s], 0, 0, 0);
      }
    }
    // C/D: col = lane&15, row = quad*4 + reg
#pragma unroll
    for (int s = 0; s < 4; ++s) {
#pragma unroll
      for (int r = 0; r < 4; ++r) {
        int row_g = r0 + rw + quad * 4 + r;
        if (row_g < N)
          dst[(size_t)row_g * 256 + coff + cw + s * 16 + m15] = f2bf(acc[s][r]);
      }
    }
    __syncthreads();
  }
}

// ---------------- GATv2: wave per node, head-major lanes, packed f32, DPP reduce ----------

__global__ __launch_bounds__(256) void k_gat(const unsigned short* __restrict__ xlb,
                                             const unsigned short* __restrict__ xrb,
                                             const float* __restrict__ att,
                                             const float* __restrict__ bias,
                                             const int* __restrict__ rowptr,
                                             const int* __restrict__ colb,
                                             float* __restrict__ out, int N) {
  const int node = blockIdx.x * 4 + (threadIdx.x >> 6);
  const int lane = threadIdx.x & 63;
  if (node >= N) return;
  float4 a4 = *(const float4*)(att + lane * 4);
  const float LOG2E = 1.4426950408889634f;
  const f32x2 a01 = {a4.x * LOG2E, a4.y * LOG2E};
  const f32x2 a23 = {a4.z * LOG2E, a4.w * LOG2E};
  const f32x2 c02 = {0.2f, 0.2f};
  const char* base = (const char*)xlb + (size_t)lane * 8;
  uint2 xru = *(const uint2*)((const char*)xrb + (size_t)node * 512 + lane * 8);
  const f32x2 xr01 = {__uint_as_float(xru.x << 16), __uint_as_float(xru.x & 0xFFFF0000u)};
  const f32x2 xr23 = {__uint_as_float(xru.y << 16), __uint_as_float(xru.y & 0xFFFF0000u)};
  int beg = rowptr[node], end = rowptr[node + 1];
  float m = -INFINITY, lsum = 0.f;
  f32x2 o01 = {0.f, 0.f}, o23 = {0.f, 0.f};
  uint2 vb_next = *(const uint2*)(base + (size_t)(unsigned)node * 512);
  int off_n = (beg < end) ? colb[beg] : 0;
  for (int e = beg; e <= end; ++e) {
    uint2 vb = vb_next;
    int off = off_n;
    if (e + 1 < end) off_n = colb[e + 1];
    if (e < end) vb_next = *(const uint2*)(base + (size_t)(unsigned)off);
    f32x2 v01 = {__uint_as_float(vb.x << 16), __uint_as_float(vb.x & 0xFFFF0000u)};
    f32x2 v23 = {__uint_as_float(vb.y << 16), __uint_as_float(vb.y & 0xFFFF0000u)};
    f32x2 s01 = v01 + xr01;
    f32x2 s23 = v23 + xr23;
    s01 = __builtin_elementwise_max(s01, s01 * c02);
    s23 = __builtin_elementwise_max(s23, s23 * c02);
    f32x2 q = __builtin_elementwise_fma(s23, a23, s01 * a01);
    float p = q.x + q.y;
    // sum over the 16-lane head group, pure VALU (quad_perm xor1, xor2; row_ror 4, 8)
    p = DPP_ADD(p, 0xB1);
    p = DPP_ADD(p, 0x4E);
    p = DPP_ADD(p, 0x124);
    p = DPP_ADD(p, 0x128);
    float nm = fmaxf(m, p);
    float sc = __builtin_amdgcn_exp2f(m - nm);
    float w = __builtin_amdgcn_exp2f(p - nm);
    lsum = fmaf(lsum, sc, w);
    f32x2 sc2 = {sc, sc}, w2 = {w, w};
    o01 = __builtin_elementwise_fma(o01, sc2, w2 * v01);
    o23 = __builtin_elementwise_fma(o23, sc2, w2 * v23);
    m = nm;
  }
  float inv = __builtin_amdgcn_rcpf(lsum);
  float rx = o01.x * inv, ry = o01.y * inv, rz = o23.x * inv, rw2 = o23.y * inv;
  rx += __shfl_xor(rx, 16, 64); rx += __shfl_xor(rx, 32, 64);
  ry += __shfl_xor(ry, 16, 64); ry += __shfl_xor(ry, 32, 64);
  rz += __shfl_xor(rz, 16, 64); rz += __shfl_xor(rz, 32, 64);
  rw2 += __shfl_xor(rw2, 16, 64); rw2 += __shfl_xor(rw2, 32, 64);
  if (lane < 16) {
    float4 b4 = *(const float4*)(bias + lane * 4);
    float4 res;
    res.x = 0.25f * rx + b4.x;
    res.y = 0.25f * ry + b4.y;
    res.z = 0.25f * rz + b4.z;
    res.w = 0.25f * rw2 + b4.w;
    *(float4*)(out + (size_t)node * 64 + lane * 4) = res;
  }
}

// ---------------- BN stats (256 blocks -> low atomic contention) ----------------

__global__ __launch_bounds__(256) void k_bn_stats(const float* __restrict__ h,
                                                  float* __restrict__ sums, int N) {
  int c = threadIdx.x & 63;
  int rl = threadIdx.x >> 6;
  float s = 0.f, q = 0.f;
  for (int n = blockIdx.x * 4 + rl; n < N; n += gridDim.x * 4) {
    float v = h[(size_t)n * 64 + c];
    s += v;
    q += v * v;
  }
  __shared__ float ls[256], lq[256];
  ls[threadIdx.x] = s;
  lq[threadIdx.x] = q;
  __syncthreads();
  if (rl == 0) {
    s = ls[c] + ls[64 + c] + ls[128 + c] + ls[192 + c];
    q = lq[c] + lq[64 + c] + lq[128 + c] + lq[192 + c];
    atomicAdd(&sums[c], s);
    atomicAdd(&sums[64 + c], q);
  }
}

// ---------------- BN apply (+GELU +residual +optional pool) ----------------

__global__ __launch_bounds__(256) void k_bn_apply(const float* __restrict__ gat,
                                                  const float* __restrict__ sums,
                                                  const float* __restrict__ g,
                                                  const float* __restrict__ be,
                                                  const float* __restrict__ resid,
                                                  float* __restrict__ out,
                                                  const int* __restrict__ batch,
                                                  float* __restrict__ pool,
                                                  int total, float inv_n) {
  int idx = blockIdx.x * 256 + threadIdx.x;
  if (idx >= total) return;
  int c = idx & 63;
  float mu = sums[c] * inv_n;
  float var = sums[64 + c] * inv_n - mu * mu;
  float inv = rsqrtf(var + 1e-5f);
  float v = g[c] * (gat[idx] - mu) * inv + be[c];
  float ge = 0.5f * v * (1.f + erff(v * 0.70710678118654752f));
  float val = ge + (resid ? resid[idx] : 0.f);
  out[idx] = val;
  if (pool) atomicAdd(&pool[(size_t)batch[idx >> 6] * 64 + c], val);
}

// ---------------- heads ----------------

__global__ void k_head(const float* __restrict__ pool, const float* __restrict__ Wmu,
                       const float* __restrict__ bmu, const float* __restrict__ Wlv,
                       const float* __restrict__ blv, float* __restrict__ out, int G) {
  int g = blockIdx.x;
  int c = threadIdx.x; // 64 threads
  __shared__ float row[64];
  row[c] = pool[(size_t)g * 64 + c];
  __syncthreads();
  float am = 0.f, al = 0.f;
  for (int k = 0; k < 64; ++k) {
    float r = row[k];
    am = fmaf(r, Wmu[k * 64 + c], am);
    al = fmaf(r, Wlv[k * 64 + c], al);
  }
  out[(size_t)g * 64 + c] = am + bmu[c];
  out[(size_t)G * 64 + (size_t)g * 64 + c] = al + blv[c];
}

// ---------------- launch ----------------

extern "C" void kernel_launch(void* const* d_in, const int* in_sizes, int n_in,
                              void* d_out, int out_size, void* d_ws, size_t ws_size,
                              hipStream_t stream) {
  const float* x    = (const float*)d_in[0];
  const int* esrc   = (const int*)d_in[1];
  const int* edst   = (const int*)d_in[2];
  const int* batch  = (const int*)d_in[3];
  const float* Wl[3]  = {(const float*)d_in[5],  (const float*)d_in[11], (const float*)d_in[17]};
  const float* Wr[3]  = {(const float*)d_in[6],  (const float*)d_in[12], (const float*)d_in[18]};
  const float* att[3] = {(const float*)d_in[7],  (const float*)d_in[13], (const float*)d_in[19]};
  const float* bia[3] = {(const float*)d_in[8],  (const float*)d_in[14], (const float*)d_in[20]};
  const float* gam[3] = {(const float*)d_in[9],  (const float*)d_in[15], (const float*)d_in[21]};
  const float* bet[3] = {(const float*)d_in[10], (const float*)d_in[16], (const float*)d_in[22]};
  const float* Wmu = (const float*)d_in[23];
  const float* bmu = (const float*)d_in[24];
  const float* Wlv = (const float*)d_in[25];
  const float* blv = (const float*)d_in[26];
  float* out = (float*)d_out;

  const int N = in_sizes[0] / 64;
  const int E = in_sizes[1];
  const int G = out_size / 128;

  char* p = (char*)d_ws;
  auto alloc = [&](size_t bytes) -> void* {
    void* r = (void*)p;
    p += (bytes + 255) & ~(size_t)255;
    return r;
  };
  // zero-init region first (one memset covers deg + bnsum + pool)
  int*   deg    = (int*)alloc((size_t)N * 4);
  float* bnsum  = (float*)alloc(3 * 128 * 4);
  float* pool   = (float*)alloc((size_t)G * 64 * 4);
  char*  zend   = p;
  unsigned short* xlb = (unsigned short*)alloc((size_t)N * 256 * 2);
  unsigned short* xrb = (unsigned short*)alloc((size_t)N * 256 * 2);
  float* hA     = (float*)alloc((size_t)N * 64 * 4);
  float* hB     = (float*)alloc((size_t)N * 64 * 4);
  float* gat    = (float*)alloc((size_t)N * 64 * 4);
  int*   rowptr = (int*)alloc((size_t)(N + 1) * 4);
  int*   cursor = (int*)alloc((size_t)N * 4);
  int*   bs     = (int*)alloc(256 * 4);
  int*   colb   = (int*)alloc((size_t)E * 4);
  unsigned short* wt = (unsigned short*)alloc(6 * 16384 * 2);

  const int nbN   = (N + 255) / 256;
  const int nbE   = (E + 255) / 256;
  const int nbGat = (N + 3) / 4;
  const int nbEl  = (N * 64 + 255) / 256;
  const int ntiles = (N + 31) / 32;
  const float inv_n = 1.f / (float)N;

  hipMemsetAsync(deg, 0, (size_t)(zend - (char*)deg), stream);

  // ---- W prep + CSR build ----
  k_wprep<<<6 * 64, 256, 0, stream>>>(Wl[0], Wr[0], Wl[1], Wr[1], Wl[2], Wr[2], wt);
  k_degree<<<nbE, 256, 0, stream>>>(edst, deg, E);
  k_scan1<<<nbN, 256, 0, stream>>>(deg, rowptr, bs, N);
  k_scan2<<<1, 256, 0, stream>>>(bs, nbN);
  k_scan3<<<nbN, 256, 0, stream>>>(rowptr, bs, cursor, N, E);
  k_fill<<<nbE, 256, 0, stream>>>(esrc, edst, cursor, colb, E);

  // ---- 3 GATv2 + BN + GELU (+res) layers ----
  const float* hin = x;
  float* houts[3] = {hA, hB, hA};
  for (int L = 0; L < 3; ++L) {
    float* hout = houts[L];
    const float* resid = (L == 0) ? nullptr : hin;
    float* poolArg = (L == 2) ? pool : nullptr;
    dim3 gmm(256, 4);
    k_mm<<<gmm, 256, 0, stream>>>(hin, wt + (size_t)L * 32768, xlb, xrb, N, ntiles);
    k_gat<<<nbGat, 256, 0, stream>>>(xlb, xrb, att[L], bia[L], rowptr, colb, gat, N);
    k_bn_stats<<<256, 256, 0, stream>>>(gat, bnsum + 128 * L, N);
    k_bn_apply<<<nbEl, 256, 0, stream>>>(gat, bnsum + 128 * L, gam[L], bet[L], resid, hout,
                                         batch, poolArg, N * 64, inv_n);
    hin = hout;
  }

  k_head<<<G, 64, 0, stream>>>(pool, Wmu, bmu, Wlv, blv, out, G);
}